// Round 1
// baseline (425.295 us; speedup 1.0000x reference)
//
#include <hip/hip_runtime.h>
#include <hip/hip_bf16.h>

#define T_ 8
#define N0_ 32
#define N1_ 32
#define SP_ (N0_*N1_)   /* 1024 spatial cells */
#define S_ (T_*SP_)     /* 8192 space-time cells */
#define E_ 256
#define P_ 16
#define NH_ 8
#define HD_ 32

// ---------------- stats: xmin & spacing per batch (matches reference fp32 ops) ------------
__global__ void stats_kernel(const float* __restrict__ tg, const float* __restrict__ grid,
                             float* __restrict__ stats, int m) {
  int lane = threadIdx.x;  // 64 threads, 1 block
  float mn0 = 1e30f, mx0 = -1e30f, mn1 = 1e30f, mx1 = -1e30f;
  for (int i = lane; i < SP_; i += 64) {
    float g0 = grid[i*2], g1 = grid[i*2+1];
    mn0 = fminf(mn0, g0); mx0 = fmaxf(mx0, g0);
    mn1 = fminf(mn1, g1); mx1 = fmaxf(mx1, g1);
  }
  for (int msk = 32; msk; msk >>= 1) {
    mn0 = fminf(mn0, __shfl_xor(mn0, msk));
    mx0 = fmaxf(mx0, __shfl_xor(mx0, msk));
    mn1 = fminf(mn1, __shfl_xor(mn1, msk));
    mx1 = fmaxf(mx1, __shfl_xor(mx1, msk));
  }
  if (lane == 0) {
    for (int b = 0; b < m; ++b) {
      float tmn = 1e30f, tmx = -1e30f;
      for (int t = 0; t < T_; ++t) {
        float v = tg[b*T_ + t];
        tmn = fminf(tmn, v); tmx = fmaxf(tmx, v);
      }
      float* st = stats + b*8;
      st[0] = tmn; st[1] = mn0; st[2] = mn1;
      st[3] = (tmx - tmn) / (float)(T_ - 1);
      st[4] = (mx0 - mn0) / (float)(N0_ - 1);
      st[5] = (mx1 - mn1) / (float)(N1_ - 1);
    }
  }
}

// ---------------- x_grid output ------------------------------------------------------------
__global__ void xgrid_kernel(const float* __restrict__ tg, const float* __restrict__ grid,
                             float* __restrict__ out, int total) {
  int idx = blockIdx.x * blockDim.x + threadIdx.x;  // over m*T*1024
  if (idx >= total) return;
  int sp = idx & (SP_ - 1);
  int bt = idx >> 10;
  out[idx*3 + 0] = tg[bt];
  out[idx*3 + 1] = grid[sp*2 + 0];
  out[idx*3 + 2] = grid[sp*2 + 1];
}

// ---------------- point -> cell assignment (fp32 op order == reference) --------------------
__global__ void assign_kernel(const float* __restrict__ x, const float* __restrict__ stats,
                              int* __restrict__ counts, int* __restrict__ cell_pts,
                              int m, int n) {
  int i = blockIdx.x * blockDim.x + threadIdx.x;
  if (i >= m*n) return;
  int b = i / n;
  int j = i - b*n;
  const float* st = stats + b*8;
  float xt = x[(size_t)i*3 + 0], x0 = x[(size_t)i*3 + 1], x1 = x[(size_t)i*3 + 2];
  float m0 = floorf((xt - st[0] + st[3]*0.5f) / st[3]);
  float m1 = floorf((x0 - st[1] + st[4]*0.5f) / st[4]);
  float m2 = floorf((x1 - st[2] + st[5]*0.5f) / st[5]);
  m0 = fminf(fmaxf(m0, 0.f), (float)(T_ - 1));
  m1 = fminf(fmaxf(m1, 0.f), (float)(N0_ - 1));
  m2 = fminf(fmaxf(m2, 0.f), (float)(N1_ - 1));
  int s = (int)m0 * SP_ + (int)m1 * N1_ + (int)m2;
  int cg = b * S_ + s;
  int old = atomicAdd(&counts[cg], 1);
  if (old < P_) cell_pts[(size_t)cg * P_ + old] = j;
}

// ---------------- per-cell: sort indices (determinism + drop policy), eff count ------------
__global__ void finalize_kernel(const int* __restrict__ counts, int* __restrict__ counts_eff,
                                int* __restrict__ cell_pts, int total) {
  int cg = blockIdx.x * blockDim.x + threadIdx.x;
  if (cg >= total) return;
  int cnt = counts[cg];
  int stored = cnt < P_ ? cnt : P_;
  int eff = cnt < (P_ - 1) ? cnt : (P_ - 1);
  int* p = cell_pts + (size_t)cg * P_;
  for (int i = 1; i < stored; ++i) {   // insertion sort ascending (original index order)
    int key = p[i]; int j = i - 1;
    while (j >= 0 && p[j] > key) { p[j+1] = p[j]; --j; }
    p[j+1] = key;
  }
  counts_eff[cg] = eff;
}

// ---------------- GEMM  C[M,256] = A[M,256] @ W[256,256], 64x64 tile, 4x4 micro ------------
template <typename InT, typename OutT>
__global__ __launch_bounds__(256) void gemm256(const InT* __restrict__ A,
                                               const float* __restrict__ W,
                                               OutT* __restrict__ C, int M) {
  __shared__ float As[16][68];
  __shared__ float Ws[16][64];
  int tid  = threadIdx.x;
  int bm   = blockIdx.x * 64;
  int bn   = blockIdx.y * 64;
  int tr   = tid >> 4;          // 0..15 (row group of 4)
  int tc   = tid & 15;          // 0..15 (col group of 4)
  int arow = tid >> 2;          // 0..63
  int akq  = (tid & 3) * 4;     // 0,4,8,12
  int wrow = tid >> 4;          // 0..15
  int wcq  = (tid & 15) * 4;    // 0..60
  float acc[4][4] = {};
  for (int k0 = 0; k0 < 256; k0 += 16) {
    float4 av;
    if constexpr (__is_same(InT, float)) {
      av = *(const float4*)&A[(size_t)(bm + arow) * 256 + k0 + akq];
    } else {
      const __hip_bfloat16* ap = (const __hip_bfloat16*)A + (size_t)(bm + arow) * 256 + k0 + akq;
      av.x = __bfloat162float(ap[0]); av.y = __bfloat162float(ap[1]);
      av.z = __bfloat162float(ap[2]); av.w = __bfloat162float(ap[3]);
    }
    As[akq+0][arow] = av.x; As[akq+1][arow] = av.y;
    As[akq+2][arow] = av.z; As[akq+3][arow] = av.w;
    *(float4*)&Ws[wrow][wcq] = *(const float4*)&W[(size_t)(k0 + wrow) * 256 + bn + wcq];
    __syncthreads();
#pragma unroll
    for (int k = 0; k < 16; ++k) {
      float a[4], b[4];
#pragma unroll
      for (int i = 0; i < 4; ++i) a[i] = As[k][tr*4 + i];
#pragma unroll
      for (int j = 0; j < 4; ++j) b[j] = Ws[k][tc*4 + j];
#pragma unroll
      for (int i = 0; i < 4; ++i)
#pragma unroll
        for (int j = 0; j < 4; ++j) acc[i][j] += a[i] * b[j];
    }
    __syncthreads();
  }
#pragma unroll
  for (int i = 0; i < 4; ++i) {
    size_t r = (size_t)(bm + tr*4 + i) * 256 + bn;
#pragma unroll
    for (int j = 0; j < 4; ++j) {
      if constexpr (__is_same(OutT, float)) C[r + tc*4 + j] = acc[i][j];
      else                                  C[r + tc*4 + j] = __float2bfloat16(acc[i][j]);
    }
  }
}

// ---------------- masked cross-attention, 1 query per cell ---------------------------------
__global__ __launch_bounds__(256) void attn_kernel(
    const float* __restrict__ q_lat, const float* __restrict__ k_lat,
    const float* __restrict__ v_lat, const __hip_bfloat16* __restrict__ kz,
    const __hip_bfloat16* __restrict__ vz, const int* __restrict__ counts_eff,
    const int* __restrict__ cell_pts, __hip_bfloat16* __restrict__ attn_out, int n) {
  const float scale = 0.17677669529663687f;  // 1/sqrt(32)
  int cellg = blockIdx.x;          // b*S + s
  int b = cellg >> 13;             // S_=8192
  int s = cellg & (S_ - 1);
  int c = s & (SP_ - 1);           // spatial index -> latent row
  int tid = threadIdx.x;           // 256 = 8 heads x 32 dims
  int h = tid >> 5;

  __shared__ float lg[NH_][17];
  __shared__ float att[NH_][17];

  int eff = counts_eff[cellg];
  const int* pts = cell_pts + (size_t)cellg * P_;

  float qv = q_lat[c*E_ + tid];

  // grid-token logit (slot 15)
  {
    float p = qv * k_lat[c*E_ + tid];
    for (int msk = 16; msk; msk >>= 1) p += __shfl_xor(p, msk);
    if ((tid & 31) == 0) lg[h][15] = p * scale;
  }
  // point logits
  for (int pp = 0; pp < eff; ++pp) {
    size_t row = ((size_t)b * n + pts[pp]) * E_;
    float p = qv * __bfloat162float(kz[row + tid]);
    for (int msk = 16; msk; msk >>= 1) p += __shfl_xor(p, msk);
    if ((tid & 31) == 0) lg[h][pp] = p * scale;
  }
  __syncthreads();
  if (tid < NH_) {
    float mx = lg[tid][15];
    for (int pp = 0; pp < eff; ++pp) mx = fmaxf(mx, lg[tid][pp]);
    float sum = 0.f;
    for (int pp = 0; pp < eff; ++pp) {
      float e = expf(lg[tid][pp] - mx);
      att[tid][pp] = e; sum += e;
    }
    float e15 = expf(lg[tid][15] - mx);
    att[tid][15] = e15; sum += e15;
    att[tid][16] = 1.f / sum;
  }
  __syncthreads();
  float acc = att[h][15] * v_lat[c*E_ + tid];
  for (int pp = 0; pp < eff; ++pp) {
    size_t row = ((size_t)b * n + pts[pp]) * E_;
    acc += att[h][pp] * __bfloat162float(vz[row + tid]);
  }
  acc *= att[h][16];
  attn_out[(size_t)cellg * E_ + tid] = __float2bfloat16(acc);
}

// -------------------------------------------------------------------------------------------
extern "C" void kernel_launch(void* const* d_in, const int* in_sizes, int n_in,
                              void* d_out, int out_size, void* d_ws, size_t ws_size,
                              hipStream_t stream) {
  const float* x       = (const float*)d_in[0];
  const float* z       = (const float*)d_in[1];
  const float* tg      = (const float*)d_in[2];
  const float* latents = (const float*)d_in[3];
  const float* grid    = (const float*)d_in[4];
  const float* Wq      = (const float*)d_in[5];
  const float* Wk      = (const float*)d_in[6];
  const float* Wv      = (const float*)d_in[7];
  const float* Wo      = (const float*)d_in[8];

  int m = in_sizes[2] / T_;              // 4
  int n = in_sizes[1] / (m * E_);        // 16384
  int MS = m * S_;                       // 32768
  float* out = (float*)d_out;

  // ---- workspace carve (256B aligned) ----
  char* w = (char*)d_ws;
  auto alloc = [&](size_t bytes) { char* p = w; w += (bytes + 255) & ~(size_t)255; return p; };
  float* stats      = (float*)alloc((size_t)m * 8 * 4);
  int*   counts     = (int*)  alloc((size_t)MS * 4);
  int*   counts_eff = (int*)  alloc((size_t)MS * 4);
  int*   cell_pts   = (int*)  alloc((size_t)MS * P_ * 4);
  float* q_lat      = (float*)alloc((size_t)SP_ * E_ * 4);
  float* k_lat      = (float*)alloc((size_t)SP_ * E_ * 4);
  float* v_lat      = (float*)alloc((size_t)SP_ * E_ * 4);
  __hip_bfloat16* kz       = (__hip_bfloat16*)alloc((size_t)m * n * E_ * 2);
  __hip_bfloat16* vz       = (__hip_bfloat16*)alloc((size_t)m * n * E_ * 2);
  __hip_bfloat16* attn_out = (__hip_bfloat16*)alloc((size_t)MS * E_ * 2);

  hipMemsetAsync(counts, 0, (size_t)MS * 4, stream);
  stats_kernel<<<1, 64, 0, stream>>>(tg, grid, stats, m);

  int tot_xg = m * T_ * SP_;             // 32768 grid sites
  xgrid_kernel<<<(tot_xg + 255)/256, 256, 0, stream>>>(tg, grid, out, tot_xg);

  assign_kernel<<<(m*n + 255)/256, 256, 0, stream>>>(x, stats, counts, cell_pts, m, n);
  finalize_kernel<<<(MS + 255)/256, 256, 0, stream>>>(counts, counts_eff, cell_pts, MS);

  // latent projections (1024 rows each)
  gemm256<float, float><<<dim3(SP_/64, 4), 256, 0, stream>>>(latents, Wq, q_lat, SP_);
  gemm256<float, float><<<dim3(SP_/64, 4), 256, 0, stream>>>(latents, Wk, k_lat, SP_);
  gemm256<float, float><<<dim3(SP_/64, 4), 256, 0, stream>>>(latents, Wv, v_lat, SP_);

  // point projections (m*n = 65536 rows)
  gemm256<float, __hip_bfloat16><<<dim3(m*n/64, 4), 256, 0, stream>>>(z, Wk, kz, m*n);
  gemm256<float, __hip_bfloat16><<<dim3(m*n/64, 4), 256, 0, stream>>>(z, Wv, vz, m*n);

  // attention per cell
  attn_kernel<<<MS, 256, 0, stream>>>(q_lat, k_lat, v_lat, kz, vz, counts_eff, cell_pts,
                                      attn_out, n);

  // output projection -> z_grid
  gemm256<__hip_bfloat16, float><<<dim3(MS/64, 4), 256, 0, stream>>>(
      attn_out, Wo, out + (size_t)tot_xg * 3, MS);
}

// Round 2
// 166.532 us; speedup vs baseline: 2.5538x; 2.5538x over previous
//
#include <hip/hip_runtime.h>
#include <hip/hip_bf16.h>

#define T_ 8
#define N0_ 32
#define N1_ 32
#define SP_ (N0_*N1_)   /* 1024 spatial cells */
#define S_ (T_*SP_)     /* 8192 space-time cells */
#define E_ 256
#define P_ 16
#define NH_ 8
#define HD_ 32

typedef __attribute__((ext_vector_type(8))) short short8;
typedef __attribute__((ext_vector_type(4))) float f32x4;
typedef __attribute__((ext_vector_type(8))) unsigned short u16x8;

__device__ __forceinline__ unsigned short f2bf(float f) {
  __hip_bfloat16 h = __float2bfloat16(f);
  return *reinterpret_cast<unsigned short*>(&h);
}

// ---------------- stats: xmin & spacing per batch (matches reference fp32 ops) ------------
__global__ void stats_kernel(const float* __restrict__ tg, const float* __restrict__ grid,
                             float* __restrict__ stats, int m) {
  int lane = threadIdx.x;  // 64 threads, 1 block
  float mn0 = 1e30f, mx0 = -1e30f, mn1 = 1e30f, mx1 = -1e30f;
  for (int i = lane; i < SP_; i += 64) {
    float g0 = grid[i*2], g1 = grid[i*2+1];
    mn0 = fminf(mn0, g0); mx0 = fmaxf(mx0, g0);
    mn1 = fminf(mn1, g1); mx1 = fmaxf(mx1, g1);
  }
  for (int msk = 32; msk; msk >>= 1) {
    mn0 = fminf(mn0, __shfl_xor(mn0, msk));
    mx0 = fmaxf(mx0, __shfl_xor(mx0, msk));
    mn1 = fminf(mn1, __shfl_xor(mn1, msk));
    mx1 = fmaxf(mx1, __shfl_xor(mx1, msk));
  }
  if (lane == 0) {
    for (int b = 0; b < m; ++b) {
      float tmn = 1e30f, tmx = -1e30f;
      for (int t = 0; t < T_; ++t) {
        float v = tg[b*T_ + t];
        tmn = fminf(tmn, v); tmx = fmaxf(tmx, v);
      }
      float* st = stats + b*8;
      st[0] = tmn; st[1] = mn0; st[2] = mn1;
      st[3] = (tmx - tmn) / (float)(T_ - 1);
      st[4] = (mx0 - mn0) / (float)(N0_ - 1);
      st[5] = (mx1 - mn1) / (float)(N1_ - 1);
    }
  }
}

// ---------------- x_grid output ------------------------------------------------------------
__global__ void xgrid_kernel(const float* __restrict__ tg, const float* __restrict__ grid,
                             float* __restrict__ out, int total) {
  int idx = blockIdx.x * blockDim.x + threadIdx.x;  // over m*T*1024
  if (idx >= total) return;
  int sp = idx & (SP_ - 1);
  int bt = idx >> 10;
  out[idx*3 + 0] = tg[bt];
  out[idx*3 + 1] = grid[sp*2 + 0];
  out[idx*3 + 2] = grid[sp*2 + 1];
}

// ---------------- point -> cell assignment (fp32 op order == reference) --------------------
__global__ void assign_kernel(const float* __restrict__ x, const float* __restrict__ stats,
                              int* __restrict__ counts, int* __restrict__ cell_pts,
                              int m, int n) {
  int i = blockIdx.x * blockDim.x + threadIdx.x;
  if (i >= m*n) return;
  int b = i / n;
  int j = i - b*n;
  const float* st = stats + b*8;
  float xt = x[(size_t)i*3 + 0], x0 = x[(size_t)i*3 + 1], x1 = x[(size_t)i*3 + 2];
  float m0 = floorf((xt - st[0] + st[3]*0.5f) / st[3]);
  float m1 = floorf((x0 - st[1] + st[4]*0.5f) / st[4]);
  float m2 = floorf((x1 - st[2] + st[5]*0.5f) / st[5]);
  m0 = fminf(fmaxf(m0, 0.f), (float)(T_ - 1));
  m1 = fminf(fmaxf(m1, 0.f), (float)(N0_ - 1));
  m2 = fminf(fmaxf(m2, 0.f), (float)(N1_ - 1));
  int s = (int)m0 * SP_ + (int)m1 * N1_ + (int)m2;
  int cg = b * S_ + s;
  int old = atomicAdd(&counts[cg], 1);
  if (old < P_) cell_pts[(size_t)cg * P_ + old] = j;
}

// ---------------- per-cell: sort indices (determinism + drop policy), eff count ------------
__global__ void finalize_kernel(const int* __restrict__ counts, int* __restrict__ counts_eff,
                                int* __restrict__ cell_pts, int total) {
  int cg = blockIdx.x * blockDim.x + threadIdx.x;
  if (cg >= total) return;
  int cnt = counts[cg];
  int stored = cnt < P_ ? cnt : P_;
  int eff = cnt < (P_ - 1) ? cnt : (P_ - 1);
  int* p = cell_pts + (size_t)cg * P_;
  for (int i = 1; i < stored; ++i) {   // insertion sort ascending (original index order)
    int key = p[i]; int j = i - 1;
    while (j >= 0 && p[j] > key) { p[j+1] = p[j]; --j; }
    p[j+1] = key;
  }
  counts_eff[cg] = eff;
}

// ---------------- weight transpose+convert: wT[1024][256] bf16 = [Wq|Wk|Wv|Wo]^T ----------
__global__ __launch_bounds__(256) void wtrans_kernel(const float* __restrict__ Wq,
                                                     const float* __restrict__ Wk,
                                                     const float* __restrict__ Wv,
                                                     const float* __restrict__ Wo,
                                                     unsigned short* __restrict__ wT) {
  int mat = blockIdx.x >> 4;
  int tile = blockIdx.x & 15;
  int tr = (tile >> 2) * 64;   // row (k) offset in W
  int tc = (tile & 3) * 64;    // col offset in W
  const float* W = mat == 0 ? Wq : mat == 1 ? Wk : mat == 2 ? Wv : Wo;
  __shared__ float ts[64][65];
  int t = threadIdx.x;
  int r = t >> 2, c0 = (t & 3) * 16;
#pragma unroll
  for (int i = 0; i < 4; ++i) {
    float4 v = *(const float4*)&W[(size_t)(tr + r) * 256 + tc + c0 + i*4];
    ts[r][c0 + i*4 + 0] = v.x; ts[r][c0 + i*4 + 1] = v.y;
    ts[r][c0 + i*4 + 2] = v.z; ts[r][c0 + i*4 + 3] = v.w;
  }
  __syncthreads();
  // out row = tc + r (original col), cols tr + c0 .. +16
  u16x8 o0, o1;
#pragma unroll
  for (int i = 0; i < 8; ++i) o0[i] = f2bf(ts[c0 + i][r]);
#pragma unroll
  for (int i = 0; i < 8; ++i) o1[i] = f2bf(ts[c0 + 8 + i][r]);
  unsigned short* dst = wT + (size_t)(mat * 256 + tc + r) * 256 + tr + c0;
  *(u16x8*)dst = o0;
  *(u16x8*)(dst + 8) = o1;
}

// ---------------- MFMA GEMM: C[M,N] = A[M,256] @ BT[N,256]^T, 128x128 tile -----------------
template <typename InT, typename OutT>
__global__ __launch_bounds__(256) void mfma_gemm(const InT* __restrict__ A,
                                                 const unsigned short* __restrict__ BT,
                                                 OutT* __restrict__ C,
                                                 int M, int ldc) {
  __shared__ unsigned short As[128 * 64];
  __shared__ unsigned short Bs[128 * 64];
  int tid = threadIdx.x;
  int bm = blockIdx.x * 128;
  int bn = blockIdx.y * 128;
  int lane = tid & 63;
  int wv = tid >> 6;
  int wr = (wv >> 1) * 64;
  int wc = (wv & 1) * 64;
  int l15 = lane & 15;
  int kgrp = (lane >> 4) * 8;

  f32x4 acc[4][4] = {};

  int srow = tid >> 3;          // 0..31
  int scol = (tid & 7) * 8;     // 0..56

  for (int kt = 0; kt < 4; ++kt) {
    int k0 = kt * 64;
#pragma unroll
    for (int i = 0; i < 4; ++i) {
      int row = srow + i * 32;
      int off = row * 128 + ((scol * 2) ^ ((row & 7) << 4));
      u16x8 av;
      if constexpr (__is_same(InT, float)) {
        const float* ap = A + (size_t)(bm + row) * 256 + k0 + scol;
        float4 f0 = *(const float4*)ap;
        float4 f1 = *(const float4*)(ap + 4);
        av[0] = f2bf(f0.x); av[1] = f2bf(f0.y); av[2] = f2bf(f0.z); av[3] = f2bf(f0.w);
        av[4] = f2bf(f1.x); av[5] = f2bf(f1.y); av[6] = f2bf(f1.z); av[7] = f2bf(f1.w);
      } else {
        av = *(const u16x8*)((const unsigned short*)A + (size_t)(bm + row) * 256 + k0 + scol);
      }
      *(u16x8*)((char*)As + off) = av;
      u16x8 bv = *(const u16x8*)(BT + (size_t)(bn + row) * 256 + k0 + scol);
      *(u16x8*)((char*)Bs + off) = bv;
    }
    __syncthreads();
#pragma unroll
    for (int kk = 0; kk < 64; kk += 32) {
      short8 af[4], bf[4];
      int kloc = kk + kgrp;
#pragma unroll
      for (int mm = 0; mm < 4; ++mm) {
        int row = wr + mm * 16 + l15;
        af[mm] = *(short8*)((char*)As + row * 128 + ((kloc * 2) ^ ((row & 7) << 4)));
      }
#pragma unroll
      for (int nn = 0; nn < 4; ++nn) {
        int col = wc + nn * 16 + l15;
        bf[nn] = *(short8*)((char*)Bs + col * 128 + ((kloc * 2) ^ ((col & 7) << 4)));
      }
#pragma unroll
      for (int mm = 0; mm < 4; ++mm)
#pragma unroll
        for (int nn = 0; nn < 4; ++nn)
          acc[mm][nn] = __builtin_amdgcn_mfma_f32_16x16x32_bf16(af[mm], bf[nn], acc[mm][nn], 0, 0, 0);
    }
    __syncthreads();
  }
  int r4 = (lane >> 4) * 4;
#pragma unroll
  for (int mm = 0; mm < 4; ++mm) {
#pragma unroll
    for (int j = 0; j < 4; ++j) {
      int grow = bm + wr + mm * 16 + r4 + j;
      size_t base = (size_t)grow * ldc + bn + wc;
#pragma unroll
      for (int nn = 0; nn < 4; ++nn) {
        float v = acc[mm][nn][j];
        if constexpr (__is_same(OutT, float)) C[base + nn * 16 + l15] = v;
        else                                  C[base + nn * 16 + l15] = __float2bfloat16(v);
      }
    }
  }
}

// ---------------- masked cross-attention, 1 query per cell ---------------------------------
__global__ __launch_bounds__(256) void attn_kernel(
    const float* __restrict__ lat,          // [1024][768]  q|k|v
    const __hip_bfloat16* __restrict__ kv,  // [m*n][512]   k|v
    const int* __restrict__ counts_eff,
    const int* __restrict__ cell_pts, __hip_bfloat16* __restrict__ attn_out, int n) {
  const float scale = 0.17677669529663687f;  // 1/sqrt(32)
  int cellg = blockIdx.x;          // b*S + s
  int b = cellg >> 13;             // S_=8192
  int s = cellg & (S_ - 1);
  int c = s & (SP_ - 1);           // spatial index -> latent row
  int tid = threadIdx.x;           // 256 = 8 heads x 32 dims
  int h = tid >> 5;

  __shared__ float lg[NH_][17];
  __shared__ float att[NH_][17];

  int eff = counts_eff[cellg];
  const int* pts = cell_pts + (size_t)cellg * P_;

  float qv = lat[c*768 + tid];

  // grid-token logit (slot 15)
  {
    float p = qv * lat[c*768 + 256 + tid];
    for (int msk = 16; msk; msk >>= 1) p += __shfl_xor(p, msk);
    if ((tid & 31) == 0) lg[h][15] = p * scale;
  }
  // point logits
  for (int pp = 0; pp < eff; ++pp) {
    size_t row = ((size_t)b * n + pts[pp]) * 512;
    float p = qv * __bfloat162float(kv[row + tid]);
    for (int msk = 16; msk; msk >>= 1) p += __shfl_xor(p, msk);
    if ((tid & 31) == 0) lg[h][pp] = p * scale;
  }
  __syncthreads();
  if (tid < NH_) {
    float mx = lg[tid][15];
    for (int pp = 0; pp < eff; ++pp) mx = fmaxf(mx, lg[tid][pp]);
    float sum = 0.f;
    for (int pp = 0; pp < eff; ++pp) {
      float e = expf(lg[tid][pp] - mx);
      att[tid][pp] = e; sum += e;
    }
    float e15 = expf(lg[tid][15] - mx);
    att[tid][15] = e15; sum += e15;
    att[tid][16] = 1.f / sum;
  }
  __syncthreads();
  float acc = att[h][15] * lat[c*768 + 512 + tid];
  for (int pp = 0; pp < eff; ++pp) {
    size_t row = ((size_t)b * n + pts[pp]) * 512;
    acc += att[h][pp] * __bfloat162float(kv[row + 256 + tid]);
  }
  acc *= att[h][16];
  attn_out[(size_t)cellg * E_ + tid] = __float2bfloat16(acc);
}

// -------------------------------------------------------------------------------------------
extern "C" void kernel_launch(void* const* d_in, const int* in_sizes, int n_in,
                              void* d_out, int out_size, void* d_ws, size_t ws_size,
                              hipStream_t stream) {
  const float* x       = (const float*)d_in[0];
  const float* z       = (const float*)d_in[1];
  const float* tg      = (const float*)d_in[2];
  const float* latents = (const float*)d_in[3];
  const float* grid    = (const float*)d_in[4];
  const float* Wq      = (const float*)d_in[5];
  const float* Wk      = (const float*)d_in[6];
  const float* Wv      = (const float*)d_in[7];
  const float* Wo      = (const float*)d_in[8];

  int m = in_sizes[2] / T_;              // 4
  int n = in_sizes[1] / (m * E_);        // 16384
  int MS = m * S_;                       // 32768
  float* out = (float*)d_out;

  // ---- workspace carve (256B aligned) ----
  char* w = (char*)d_ws;
  auto alloc = [&](size_t bytes) { char* p = w; w += (bytes + 255) & ~(size_t)255; return p; };
  float* stats      = (float*)alloc((size_t)m * 8 * 4);
  int*   counts     = (int*)  alloc((size_t)MS * 4);
  int*   counts_eff = (int*)  alloc((size_t)MS * 4);
  int*   cell_pts   = (int*)  alloc((size_t)MS * P_ * 4);
  unsigned short* wT = (unsigned short*)alloc((size_t)1024 * 256 * 2);
  float* lat        = (float*)alloc((size_t)SP_ * 768 * 4);
  __hip_bfloat16* kv       = (__hip_bfloat16*)alloc((size_t)m * n * 512 * 2);
  __hip_bfloat16* attn_out = (__hip_bfloat16*)alloc((size_t)MS * E_ * 2);

  hipMemsetAsync(counts, 0, (size_t)MS * 4, stream);
  stats_kernel<<<1, 64, 0, stream>>>(tg, grid, stats, m);

  int tot_xg = m * T_ * SP_;             // 32768 grid sites
  xgrid_kernel<<<(tot_xg + 255)/256, 256, 0, stream>>>(tg, grid, out, tot_xg);

  assign_kernel<<<(m*n + 255)/256, 256, 0, stream>>>(x, stats, counts, cell_pts, m, n);
  finalize_kernel<<<(MS + 255)/256, 256, 0, stream>>>(counts, counts_eff, cell_pts, MS);

  // weights: transpose + convert to bf16  [Wq|Wk|Wv|Wo]^T
  wtrans_kernel<<<64, 256, 0, stream>>>(Wq, Wk, Wv, Wo, wT);

  // latent projections fused: lat[1024,768] = latents @ [Wq|Wk|Wv]
  mfma_gemm<float, float><<<dim3(SP_/128, 6), 256, 0, stream>>>(latents, wT, lat, SP_, 768);

  // point projections fused: kv[m*n,512] = z @ [Wk|Wv]
  mfma_gemm<float, __hip_bfloat16><<<dim3(m*n/128, 4), 256, 0, stream>>>(
      z, wT + (size_t)256*256, (__hip_bfloat16*)kv, m*n, 512);

  // attention per cell
  attn_kernel<<<MS, 256, 0, stream>>>(lat, kv, counts_eff, cell_pts, attn_out, n);

  // output projection -> z_grid
  mfma_gemm<__hip_bfloat16, float><<<dim3(MS/128, 2), 256, 0, stream>>>(
      attn_out, wT + (size_t)768*256, out + (size_t)tot_xg * 3, MS, 256);
}

// Round 3
// 107.292 us; speedup vs baseline: 3.9639x; 1.5521x over previous
//
#include <hip/hip_runtime.h>
#include <hip/hip_bf16.h>

#define T_ 8
#define N0_ 32
#define N1_ 32
#define SP_ (N0_*N1_)   /* 1024 spatial cells */
#define S_ (T_*SP_)     /* 8192 space-time cells */
#define E_ 256
#define P_ 16
#define NH_ 8
#define HD_ 32

typedef __attribute__((ext_vector_type(8))) short short8;
typedef __attribute__((ext_vector_type(4))) float f32x4;
typedef __attribute__((ext_vector_type(8))) unsigned short u16x8;

__device__ __forceinline__ unsigned short f2bf(float f) {
  __hip_bfloat16 h = __float2bfloat16(f);
  return *reinterpret_cast<unsigned short*>(&h);
}
__device__ __forceinline__ float bf2f(unsigned short u) {
  return __uint_as_float((unsigned)u << 16);
}

// ---------------- stats: xmin & spacing per batch (matches reference fp32 ops) ------------
__global__ void stats_kernel(const float* __restrict__ tg, const float* __restrict__ grid,
                             float* __restrict__ stats, int m) {
  int lane = threadIdx.x;  // 64 threads, 1 block
  float mn0 = 1e30f, mx0 = -1e30f, mn1 = 1e30f, mx1 = -1e30f;
  for (int i = lane; i < SP_; i += 64) {
    float g0 = grid[i*2], g1 = grid[i*2+1];
    mn0 = fminf(mn0, g0); mx0 = fmaxf(mx0, g0);
    mn1 = fminf(mn1, g1); mx1 = fmaxf(mx1, g1);
  }
  for (int msk = 32; msk; msk >>= 1) {
    mn0 = fminf(mn0, __shfl_xor(mn0, msk));
    mx0 = fmaxf(mx0, __shfl_xor(mx0, msk));
    mn1 = fminf(mn1, __shfl_xor(mn1, msk));
    mx1 = fmaxf(mx1, __shfl_xor(mx1, msk));
  }
  if (lane == 0) {
    for (int b = 0; b < m; ++b) {
      float tmn = 1e30f, tmx = -1e30f;
      for (int t = 0; t < T_; ++t) {
        float v = tg[b*T_ + t];
        tmn = fminf(tmn, v); tmx = fmaxf(tmx, v);
      }
      float* st = stats + b*8;
      st[0] = tmn; st[1] = mn0; st[2] = mn1;
      st[3] = (tmx - tmn) / (float)(T_ - 1);
      st[4] = (mx0 - mn0) / (float)(N0_ - 1);
      st[5] = (mx1 - mn1) / (float)(N1_ - 1);
    }
  }
}

// ---------------- x_grid output ------------------------------------------------------------
__global__ void xgrid_kernel(const float* __restrict__ tg, const float* __restrict__ grid,
                             float* __restrict__ out, int total) {
  int idx = blockIdx.x * blockDim.x + threadIdx.x;  // over m*T*1024
  if (idx >= total) return;
  int sp = idx & (SP_ - 1);
  int bt = idx >> 10;
  out[idx*3 + 0] = tg[bt];
  out[idx*3 + 1] = grid[sp*2 + 0];
  out[idx*3 + 2] = grid[sp*2 + 1];
}

// ---------------- point -> cell assignment (fp32 op order == reference) --------------------
__global__ void assign_kernel(const float* __restrict__ x, const float* __restrict__ stats,
                              int* __restrict__ counts, int* __restrict__ cell_raw,
                              int m, int n) {
  int i = blockIdx.x * blockDim.x + threadIdx.x;
  if (i >= m*n) return;
  int b = i / n;
  int j = i - b*n;
  const float* st = stats + b*8;
  float xt = x[(size_t)i*3 + 0], x0 = x[(size_t)i*3 + 1], x1 = x[(size_t)i*3 + 2];
  float m0 = floorf((xt - st[0] + st[3]*0.5f) / st[3]);
  float m1 = floorf((x0 - st[1] + st[4]*0.5f) / st[4]);
  float m2 = floorf((x1 - st[2] + st[5]*0.5f) / st[5]);
  m0 = fminf(fmaxf(m0, 0.f), (float)(T_ - 1));
  m1 = fminf(fmaxf(m1, 0.f), (float)(N0_ - 1));
  m2 = fminf(fmaxf(m2, 0.f), (float)(N1_ - 1));
  int s = (int)m0 * SP_ + (int)m1 * N1_ + (int)m2;
  int cg = b * S_ + s;
  int old = atomicAdd(&counts[cg], 1);
  if (old < P_) cell_raw[(size_t)cg * P_ + old] = j;
}

// ------- per-cell: sort indices (determinism + exact first-15 drop), pack eff+pts ---------
__global__ void finalize_kernel(const int* __restrict__ counts, int* __restrict__ cell_raw,
                                int* __restrict__ pts2, int total) {
  int cg = blockIdx.x * blockDim.x + threadIdx.x;
  if (cg >= total) return;
  int cnt = counts[cg];
  int stored = cnt < P_ ? cnt : P_;
  int eff = cnt < (P_ - 1) ? cnt : (P_ - 1);
  int* p = cell_raw + (size_t)cg * P_;
  for (int i = 1; i < stored; ++i) {   // insertion sort ascending (original index order)
    int key = p[i]; int j = i - 1;
    while (j >= 0 && p[j] > key) { p[j+1] = p[j]; --j; }
    p[j+1] = key;
  }
  int* o = pts2 + (size_t)cg * P_;
  o[0] = eff;
  for (int i = 0; i < eff; ++i) o[1 + i] = p[i];
}

// ---------------- weight transpose+convert: wT[1024][256] bf16 = [Wq|Wk|Wv|Wo]^T ----------
__global__ __launch_bounds__(256) void wtrans_kernel(const float* __restrict__ Wq,
                                                     const float* __restrict__ Wk,
                                                     const float* __restrict__ Wv,
                                                     const float* __restrict__ Wo,
                                                     unsigned short* __restrict__ wT) {
  int mat = blockIdx.x >> 4;
  int tile = blockIdx.x & 15;
  int tr = (tile >> 2) * 64;   // row (k) offset in W
  int tc = (tile & 3) * 64;    // col offset in W
  const float* W = mat == 0 ? Wq : mat == 1 ? Wk : mat == 2 ? Wv : Wo;
  __shared__ float ts[64][65];
  int t = threadIdx.x;
  int r = t >> 2, c0 = (t & 3) * 16;
#pragma unroll
  for (int i = 0; i < 4; ++i) {
    float4 v = *(const float4*)&W[(size_t)(tr + r) * 256 + tc + c0 + i*4];
    ts[r][c0 + i*4 + 0] = v.x; ts[r][c0 + i*4 + 1] = v.y;
    ts[r][c0 + i*4 + 2] = v.z; ts[r][c0 + i*4 + 3] = v.w;
  }
  __syncthreads();
  u16x8 o0, o1;
#pragma unroll
  for (int i = 0; i < 8; ++i) o0[i] = f2bf(ts[c0 + i][r]);
#pragma unroll
  for (int i = 0; i < 8; ++i) o1[i] = f2bf(ts[c0 + 8 + i][r]);
  unsigned short* dst = wT + (size_t)(mat * 256 + tc + r) * 256 + tr + c0;
  *(u16x8*)dst = o0;
  *(u16x8*)(dst + 8) = o1;
}

// ---------------- MFMA GEMM: C[M,N] = A[M,256] @ BT[N,256]^T, 128x128 tile -----------------
// 1D grid, XCD-chunked swizzle (col-panel fastest within an XCD's slot sequence).
template <typename InT, typename OutT>
__global__ __launch_bounds__(256) void mfma_gemm(const InT* __restrict__ A,
                                                 const unsigned short* __restrict__ BT,
                                                 OutT* __restrict__ C,
                                                 int M, int ldc, int CP) {
  __shared__ unsigned short As[128 * 64];
  __shared__ unsigned short Bs[128 * 64];
  int nb = gridDim.x;
  int bid = blockIdx.x;
  int L = bid;
  if ((nb & 7) == 0) L = (bid & 7) * (nb >> 3) + (bid >> 3);
  int rp = L / CP;
  int cp = L - rp * CP;
  int bm = rp * 128;
  int bn = cp * 128;
  int tid = threadIdx.x;
  int lane = tid & 63;
  int wv = tid >> 6;
  int wr = (wv >> 1) * 64;
  int wc = (wv & 1) * 64;
  int l15 = lane & 15;
  int kgrp = (lane >> 4) * 8;

  f32x4 acc[4][4] = {};

  int srow = tid >> 3;          // 0..31
  int scol = (tid & 7) * 8;     // 0..56

  for (int kt = 0; kt < 4; ++kt) {
    int k0 = kt * 64;
#pragma unroll
    for (int i = 0; i < 4; ++i) {
      int row = srow + i * 32;
      int off = row * 128 + ((scol * 2) ^ ((row & 7) << 4));
      u16x8 av;
      if constexpr (__is_same(InT, float)) {
        const float* ap = A + (size_t)(bm + row) * 256 + k0 + scol;
        float4 f0 = *(const float4*)ap;
        float4 f1 = *(const float4*)(ap + 4);
        av[0] = f2bf(f0.x); av[1] = f2bf(f0.y); av[2] = f2bf(f0.z); av[3] = f2bf(f0.w);
        av[4] = f2bf(f1.x); av[5] = f2bf(f1.y); av[6] = f2bf(f1.z); av[7] = f2bf(f1.w);
      } else {
        av = *(const u16x8*)((const unsigned short*)A + (size_t)(bm + row) * 256 + k0 + scol);
      }
      *(u16x8*)((char*)As + off) = av;
      u16x8 bv = *(const u16x8*)(BT + (size_t)(bn + row) * 256 + k0 + scol);
      *(u16x8*)((char*)Bs + off) = bv;
    }
    __syncthreads();
#pragma unroll
    for (int kk = 0; kk < 64; kk += 32) {
      short8 af[4], bf[4];
      int kloc = kk + kgrp;
#pragma unroll
      for (int mm = 0; mm < 4; ++mm) {
        int row = wr + mm * 16 + l15;
        af[mm] = *(short8*)((char*)As + row * 128 + ((kloc * 2) ^ ((row & 7) << 4)));
      }
#pragma unroll
      for (int nn = 0; nn < 4; ++nn) {
        int col = wc + nn * 16 + l15;
        bf[nn] = *(short8*)((char*)Bs + col * 128 + ((kloc * 2) ^ ((col & 7) << 4)));
      }
#pragma unroll
      for (int mm = 0; mm < 4; ++mm)
#pragma unroll
        for (int nn = 0; nn < 4; ++nn)
          acc[mm][nn] = __builtin_amdgcn_mfma_f32_16x16x32_bf16(af[mm], bf[nn], acc[mm][nn], 0, 0, 0);
    }
    __syncthreads();
  }
  int r4 = (lane >> 4) * 4;
#pragma unroll
  for (int mm = 0; mm < 4; ++mm) {
#pragma unroll
    for (int j = 0; j < 4; ++j) {
      int grow = bm + wr + mm * 16 + r4 + j;
      size_t base = (size_t)grow * ldc + bn + wc;
#pragma unroll
      for (int nn = 0; nn < 4; ++nn) {
        float v = acc[mm][nn][j];
        if constexpr (__is_same(OutT, float)) C[base + nn * 16 + l15] = v;
        else                                  C[base + nn * 16 + l15] = __float2bfloat16(v);
      }
    }
  }
}

// ---------------- masked cross-attention: one wave per cell, online softmax ---------------
__global__ __launch_bounds__(256) void attn_kernel(
    const float* __restrict__ lat,          // [1024][768]  q|k|v
    const __hip_bfloat16* __restrict__ kv,  // [m*n][512]   k|v
    const int* __restrict__ pts2,           // [MS][16]: w0=eff, w1..15 sorted pt indices
    __hip_bfloat16* __restrict__ attn_out, int n) {
  const float scale = 0.17677669529663687f;  // 1/sqrt(32)
  int wid = threadIdx.x >> 6;
  int lane = threadIdx.x & 63;
  int cellg = blockIdx.x * 4 + wid;
  int b = cellg >> 13;                 // S_=8192, cells per batch
  int c = cellg & (SP_ - 1);           // spatial index -> latent row
  int d0 = lane << 2;                  // 4 dims per lane

  const int* pp = pts2 + (size_t)cellg * P_;
  int4 h0 = *(const int4*)pp;          // eff, pt0, pt1, pt2 (broadcast load)
  int eff = h0.x;

  const float* latc = lat + c * 768 + d0;
  float4 q  = *(const float4*)latc;
  float4 kl = *(const float4*)(latc + 256);
  float4 vl = *(const float4*)(latc + 512);

  // grid-token logit -> init online-softmax state
  float part = q.x*kl.x + q.y*kl.y + q.z*kl.z + q.w*kl.w;
  part += __shfl_xor(part, 1);
  part += __shfl_xor(part, 2);
  part += __shfl_xor(part, 4);         // head-local (8 lanes = 32 dims)
  float mx = part * scale;
  float ssum = 1.f;
  float4 acc = vl;

  const unsigned short* kvp = (const unsigned short*)kv;
  size_t bbase = (size_t)b * n;

  int pt[4]; pt[0] = h0.y; pt[1] = h0.z; pt[2] = h0.w; pt[3] = 0;
  int done = 0, cap = 3;
  while (done < eff) {
    int np = eff - done; if (np > cap) np = cap;
    ushort4 kr[4], vr[4];
#pragma unroll
    for (int i = 0; i < 4; ++i) if (i < np) {
      size_t row = (bbase + (size_t)pt[i]) * 512;
      kr[i] = *(const ushort4*)(kvp + row + d0);
      vr[i] = *(const ushort4*)(kvp + row + 256 + d0);
    }
#pragma unroll
    for (int i = 0; i < 4; ++i) if (i < np) {
      float p = q.x*bf2f(kr[i].x) + q.y*bf2f(kr[i].y) + q.z*bf2f(kr[i].z) + q.w*bf2f(kr[i].w);
      p += __shfl_xor(p, 1);
      p += __shfl_xor(p, 2);
      p += __shfl_xor(p, 4);
      p *= scale;
      float m2 = fmaxf(mx, p);
      float corr = __expf(mx - m2);
      float e = __expf(p - m2);
      ssum = ssum * corr + e;
      acc.x = acc.x * corr + e * bf2f(vr[i].x);
      acc.y = acc.y * corr + e * bf2f(vr[i].y);
      acc.z = acc.z * corr + e * bf2f(vr[i].z);
      acc.w = acc.w * corr + e * bf2f(vr[i].w);
      mx = m2;
    }
    done += np;
    cap = 4;
    if (done < eff) {
      int4 h = *(const int4*)(pp + 1 + done);   // done in {3,7,11} -> aligned
      pt[0] = h.x; pt[1] = h.y; pt[2] = h.z; pt[3] = h.w;
    }
  }
  float inv = 1.f / ssum;
  ushort4 o;
  o.x = f2bf(acc.x * inv); o.y = f2bf(acc.y * inv);
  o.z = f2bf(acc.z * inv); o.w = f2bf(acc.w * inv);
  *(ushort4*)((unsigned short*)attn_out + (size_t)cellg * E_ + d0) = o;
}

// -------------------------------------------------------------------------------------------
extern "C" void kernel_launch(void* const* d_in, const int* in_sizes, int n_in,
                              void* d_out, int out_size, void* d_ws, size_t ws_size,
                              hipStream_t stream) {
  const float* x       = (const float*)d_in[0];
  const float* z       = (const float*)d_in[1];
  const float* tg      = (const float*)d_in[2];
  const float* latents = (const float*)d_in[3];
  const float* grid    = (const float*)d_in[4];
  const float* Wq      = (const float*)d_in[5];
  const float* Wk      = (const float*)d_in[6];
  const float* Wv      = (const float*)d_in[7];
  const float* Wo      = (const float*)d_in[8];

  int m = in_sizes[2] / T_;              // 4
  int n = in_sizes[1] / (m * E_);        // 16384
  int MS = m * S_;                       // 32768
  float* out = (float*)d_out;

  // ---- workspace carve (256B aligned) ----
  char* w = (char*)d_ws;
  auto alloc = [&](size_t bytes) { char* p = w; w += (bytes + 255) & ~(size_t)255; return p; };
  float* stats      = (float*)alloc((size_t)m * 8 * 4);
  int*   counts     = (int*)  alloc((size_t)MS * 4);
  int*   cell_raw   = (int*)  alloc((size_t)MS * P_ * 4);
  int*   pts2       = (int*)  alloc((size_t)MS * P_ * 4);
  unsigned short* wT = (unsigned short*)alloc((size_t)1024 * 256 * 2);
  float* lat        = (float*)alloc((size_t)SP_ * 768 * 4);
  __hip_bfloat16* kv       = (__hip_bfloat16*)alloc((size_t)m * n * 512 * 2);
  __hip_bfloat16* attn_out = (__hip_bfloat16*)alloc((size_t)MS * E_ * 2);

  hipMemsetAsync(counts, 0, (size_t)MS * 4, stream);
  stats_kernel<<<1, 64, 0, stream>>>(tg, grid, stats, m);

  int tot_xg = m * T_ * SP_;             // 32768 grid sites
  xgrid_kernel<<<(tot_xg + 255)/256, 256, 0, stream>>>(tg, grid, out, tot_xg);

  assign_kernel<<<(m*n + 255)/256, 256, 0, stream>>>(x, stats, counts, cell_raw, m, n);
  finalize_kernel<<<(MS + 255)/256, 256, 0, stream>>>(counts, cell_raw, pts2, MS);

  // weights: transpose + convert to bf16  [Wq|Wk|Wv|Wo]^T
  wtrans_kernel<<<64, 256, 0, stream>>>(Wq, Wk, Wv, Wo, wT);

  // latent projections fused: lat[1024,768] = latents @ [Wq|Wk|Wv]   (8 rp x 6 cp = 48 blocks)
  mfma_gemm<float, float><<<48, 256, 0, stream>>>(latents, wT, lat, SP_, 768, 6);

  // point projections fused: kv[m*n,512] = z @ [Wk|Wv]   (512 rp x 4 cp = 2048 blocks)
  mfma_gemm<float, __hip_bfloat16><<<2048, 256, 0, stream>>>(
      z, wT + (size_t)256*256, (__hip_bfloat16*)kv, m*n, 512, 4);

  // attention: one wave per cell
  attn_kernel<<<MS/4, 256, 0, stream>>>(lat, kv, pts2, attn_out, n);

  // output projection -> z_grid   (256 rp x 2 cp = 512 blocks)
  mfma_gemm<__hip_bfloat16, float><<<512, 256, 0, stream>>>(
      attn_out, wT + (size_t)768*256, out + (size_t)tot_xg * 3, MS, 256, 2);
}